// Round 1
// baseline (1175.594 us; speedup 1.0000x reference)
//
#include <hip/hip_runtime.h>
#include <math.h>

#define B 2048
#define T 512
#define D 178
#define H 5
#define G 20   // 4*H

// ------------------------------------------------------------------
// Kernel 1: input projection
//   xg[t][g][b] = (b_ih[g] + b_hh[g]) + sum_d x[b,t,d] * w_ih[g,d]
// Grid: (B*T)/64 blocks of 256 threads.
// Block handles 64 rows = fixed t, 64 consecutive b (rt = t*B + b).
// x rows are staged into LDS coalesced; compute reads via ds_read_b128.
// ------------------------------------------------------------------
#define TILE 64
#define XS_STRIDE 180   // pad 178 -> 180 (16B-aligned rows, benign bank aliasing)

__global__ __launch_bounds__(256) void proj_kernel(
    const float* __restrict__ x, const float* __restrict__ w_ih,
    const float* __restrict__ b_ih, const float* __restrict__ b_hh,
    float* __restrict__ xg)
{
    __shared__ __align__(16) float xs[TILE * XS_STRIDE];   // 45 KB
    __shared__ __align__(16) float ws[G * XS_STRIDE];      // 14.1 KB
    __shared__ float bs[G];

    const int tid = threadIdx.x;
    const int rt0 = blockIdx.x * TILE;
    const int t   = rt0 >> 11;        // rt0 / B   (B = 2048)
    const int b0  = rt0 & (B - 1);    // multiple of 64, so tile never crosses t

    // stage w_ih (row-major 20x178) into padded ws[g][d]
    for (int idx = tid; idx < G * D; idx += 256) {
        int g = idx / D, d = idx - g * D;
        ws[g * XS_STRIDE + d] = w_ih[idx];
    }
    if (tid < G) bs[tid] = b_ih[tid] + b_hh[tid];

    // stage 64 x-rows: each wave stages 16 rows, 4 lanes per row along d
    {
        const int lane = tid & 63;
        const int q    = tid >> 6;
        const int row  = q * 16 + (lane >> 2);
        const int dg   = lane & 3;
        const float* xrow = x + ((size_t)(b0 + row) * T + t) * D;
        float* xsr = &xs[row * XS_STRIDE];
        #pragma unroll
        for (int i = 0; i < 23; ++i) {
            int d = dg * 2 + i * 8;          // all even d in [0,184)
            if (d < D) {
                float2 v = *(const float2*)(xrow + d);   // rows are 8B-aligned
                xsr[d]     = v.x;
                xsr[d + 1] = v.y;
            }
        }
    }
    __syncthreads();

    // compute: thread = (row j, gate-group gg of 5 gates)
    const int j  = tid >> 2;
    const int gg = tid & 3;
    float acc[5];
    #pragma unroll
    for (int gi = 0; gi < 5; ++gi) acc[gi] = bs[gg * 5 + gi];

    const float* xr = &xs[j * XS_STRIDE];
    const float* wr = &ws[gg * 5 * XS_STRIDE];
    #pragma unroll 4
    for (int i = 0; i < 44; ++i) {           // d = 0..175 in float4 steps
        float4 xv = *(const float4*)(xr + 4 * i);
        #pragma unroll
        for (int gi = 0; gi < 5; ++gi) {
            float4 wv = *(const float4*)(wr + gi * XS_STRIDE + 4 * i);
            acc[gi] += xv.x * wv.x + xv.y * wv.y + xv.z * wv.z + xv.w * wv.w;
        }
    }
    {   // tail d = 176,177
        float2 xv = *(const float2*)(xr + 176);
        #pragma unroll
        for (int gi = 0; gi < 5; ++gi) {
            float2 wv = *(const float2*)(wr + gi * XS_STRIDE + 176);
            acc[gi] += xv.x * wv.x + xv.y * wv.y;
        }
    }

    // coalesced plane-major writes: xg[(t*20+g)*B + b]
    size_t base = (size_t)t * G * B + b0 + j;
    #pragma unroll
    for (int gi = 0; gi < 5; ++gi)
        xg[base + (size_t)(gg * 5 + gi) * B] = acc[gi];
}

// ------------------------------------------------------------------
// Kernel 2: sequential LSTM scan + fused FC epilogue.
// 5 lanes per batch element: lane k owns element k => gates k, k+5, k+10,
// k+15 (i,f,g,o of element k) all on one lane -> no cross-lane gather for
// the cell update; only h (5 values) is broadcast back per step via shfl.
// xg loads are prefetched one 8-step chunk ahead.
// ------------------------------------------------------------------
__device__ __forceinline__ float frcp(float v) { return __builtin_amdgcn_rcpf(v); }
__device__ __forceinline__ float sigm(float v) { return frcp(1.f + __expf(-v)); }
__device__ __forceinline__ float tanh_fast(float v) {
    float e = __expf(-2.f * v);          // |v| bounded ~40 here -> no overflow
    return (1.f - e) * frcp(1.f + e);
}

#define CH 8            // prefetch chunk (steps)
#define GPB 12          // batch groups per 64-lane wave (12*5 = 60 lanes used)

__global__ __launch_bounds__(64) void scan_kernel(
    const float* __restrict__ xg, const float* __restrict__ w_hh,
    const float* __restrict__ w_fc, const float* __restrict__ b_fc,
    float* __restrict__ out)
{
    const int lane = threadIdx.x;
    int grp = lane / 5;
    int k   = lane - grp * 5;
    bool valid = (grp < GPB);
    if (!valid) { grp = 0; k = 0; }
    int b = blockIdx.x * GPB + grp;
    bool active = valid && (b < B);
    int bb = active ? b : 0;

    // per-lane weights: w_hh rows k, k+5, k+10, k+15 (i,f,g,o of element k)
    float whh[4][5];
    #pragma unroll
    for (int r = 0; r < 4; ++r)
        #pragma unroll
        for (int jj = 0; jj < 5; ++jj)
            whh[r][jj] = w_hh[(k + 5 * r) * H + jj];
    float wfc[5];
    #pragma unroll
    for (int jj = 0; jj < 5; ++jj) wfc[jj] = w_fc[k * H + jj];
    const float bfc = b_fc[k];

    float h[5] = {0.f, 0.f, 0.f, 0.f, 0.f};
    float c = 0.f;
    const int srcbase = grp * 5;

    const float* gbase = xg + (size_t)k * B + bb;   // + t*(G*B) + r*(5*B)

    float cur[CH][4], nxt[CH][4];
    #pragma unroll
    for (int s = 0; s < CH; ++s)
        #pragma unroll
        for (int r = 0; r < 4; ++r)
            cur[s][r] = gbase[(size_t)s * (G * B) + (size_t)r * (H * B)];

    for (int ch = 0; ch < T / CH; ++ch) {
        if (ch + 1 < T / CH) {
            const float* nb = gbase + (size_t)(ch + 1) * CH * (G * B);
            #pragma unroll
            for (int s = 0; s < CH; ++s)
                #pragma unroll
                for (int r = 0; r < 4; ++r)
                    nxt[s][r] = nb[(size_t)s * (G * B) + (size_t)r * (H * B)];
        }
        #pragma unroll
        for (int s = 0; s < CH; ++s) {
            float gi_ = cur[s][0], gf_ = cur[s][1], gg_ = cur[s][2], go_ = cur[s][3];
            #pragma unroll
            for (int jj = 0; jj < 5; ++jj) {
                gi_ += whh[0][jj] * h[jj];
                gf_ += whh[1][jj] * h[jj];
                gg_ += whh[2][jj] * h[jj];
                go_ += whh[3][jj] * h[jj];
            }
            float iv = sigm(gi_);
            float fv = sigm(gf_);
            float ov = sigm(go_);
            float gv = tanh_fast(gg_);
            c = fv * c + iv * gv;
            float hk = ov * tanh_fast(c);
            // broadcast the group's 5 new h values to all 5 lanes
            #pragma unroll
            for (int jj = 0; jj < 5; ++jj)
                h[jj] = __shfl(hk, srcbase + jj, 64);
        }
        #pragma unroll
        for (int s = 0; s < CH; ++s)
            #pragma unroll
            for (int r = 0; r < 4; ++r)
                cur[s][r] = nxt[s][r];
    }

    // fused FC: out[b][k] = b_fc[k] + sum_j relu(h[j]) * w_fc[k][j]
    float o = bfc;
    #pragma unroll
    for (int jj = 0; jj < 5; ++jj)
        o += fmaxf(h[jj], 0.f) * wfc[jj];
    if (active) out[(size_t)b * H + k] = o;
}

// ------------------------------------------------------------------
extern "C" void kernel_launch(void* const* d_in, const int* in_sizes, int n_in,
                              void* d_out, int out_size, void* d_ws, size_t ws_size,
                              hipStream_t stream)
{
    const float* x    = (const float*)d_in[0];
    const float* w_ih = (const float*)d_in[1];
    const float* w_hh = (const float*)d_in[2];
    const float* b_ih = (const float*)d_in[3];
    const float* b_hh = (const float*)d_in[4];
    const float* w_fc = (const float*)d_in[5];
    const float* b_fc = (const float*)d_in[6];
    float* out = (float*)d_out;
    float* xg  = (float*)d_ws;   // needs T*G*B*4 = 80 MiB of workspace

    proj_kernel<<<(B * T) / TILE, 256, 0, stream>>>(x, w_ih, b_ih, b_hh, xg);
    scan_kernel<<<(B + GPB - 1) / GPB, 64, 0, stream>>>(xg, w_hh, w_fc, b_fc, out);
}